// Round 8
// baseline (131.666 us; speedup 1.0000x reference)
//
#include <hip/hip_runtime.h>
#include <math.h>

// MatchNet: 4-layer tanh MLP (6->20->20->20->8) + 150-iter PDHG QP solve.
// Round-8: 8 LANES PER SAMPLE (262144 thr = 4096 waves = 4/SIMD), DPP-only
// cross-lane. Cross-round evidence (R4 vs R7): per-wave issue cadence is
// ~7.5 cyc/instr regardless of code shape; throughput scales with resident
// waves until VALU saturates -> maximize waves, minimize instrs/wave.
// Lane permutations chosen so S's structure becomes DPP-friendly:
//   x layout  pi  = [0,5,3,4,1,6,2,7]  (xor1 pairs P05,P34,P16,P27)
//   l1 layout rho = [0,1,2,3,5,4,-,-]  (xor1 pairs Q01,Q23,Q45)
// => every S row = pair+single; S^T cols = pair or 2 singles. All gathers
// are quad_perm + row_half_mirror (lane^7, stays inside 8-lane groups).
// All DPPs unconditional (R6 lesson); selects are value-cndmasks.

#define NITERS 150

__device__ __forceinline__ float ftanh(float a) {
    float e = __expf(2.0f * a);
    return fmaf(-2.0f, __builtin_amdgcn_rcpf(e + 1.0f), 1.0f);
}

template<int CTRL>
__device__ __forceinline__ float dppmov(float x) {
    int xi = __builtin_bit_cast(int, x);
    int yi = __builtin_amdgcn_update_dpp(0, xi, CTRL, 0xF, 0xF, true);
    return __builtin_bit_cast(float, yi);
}
template<int P0, int P1, int P2, int P3>
__device__ __forceinline__ float qp(float x) {
    return dppmov<(P0) | ((P1) << 2) | ((P2) << 4) | ((P3) << 6)>(x);
}
#define HMIR 0x141   // row_half_mirror: lane k -> k^7 within each 8-lane half

#define FOR20(M) M(0) M(1) M(2) M(3) M(4) M(5) M(6) M(7) M(8) M(9) \
                 M(10) M(11) M(12) M(13) M(14) M(15) M(16) M(17) M(18) M(19)
#define FOR8(M)  M(0) M(1) M(2) M(3) M(4) M(5) M(6) M(7)

#define DOT20(W, base, H) \
  ( (fmaf(W[(base)+0],H##0,  fmaf(W[(base)+1],H##1,  fmaf(W[(base)+2],H##2,  fmaf(W[(base)+3],H##3,  W[(base)+4]*H##4)))) \
   + fmaf(W[(base)+5],H##5,  fmaf(W[(base)+6],H##6,  fmaf(W[(base)+7],H##7,  fmaf(W[(base)+8],H##8,  W[(base)+9]*H##9))))) \
  + (fmaf(W[(base)+10],H##10, fmaf(W[(base)+11],H##11, fmaf(W[(base)+12],H##12, fmaf(W[(base)+13],H##13, W[(base)+14]*H##14)))) \
   + fmaf(W[(base)+15],H##15, fmaf(W[(base)+16],H##16, fmaf(W[(base)+17],H##17, fmaf(W[(base)+18],H##18, W[(base)+19]*H##19))))) )

#define DOT6(W, base, P) \
  ( fmaf(W[(base)+0],P##0, fmaf(W[(base)+1],P##1, W[(base)+2]*P##2)) \
  + fmaf(W[(base)+3],P##3, fmaf(W[(base)+4],P##4, W[(base)+5]*P##5)) )

__global__ __launch_bounds__(256, 4)
void matchnet_kernel(
    const float* __restrict__ X,
    const float* __restrict__ W1, const float* __restrict__ b1,
    const float* __restrict__ W2, const float* __restrict__ b2,
    const float* __restrict__ W3, const float* __restrict__ b3,
    const float* __restrict__ W4, const float* __restrict__ b4,
    float* __restrict__ out, int B)
{
    const int tid = blockIdx.x * 256 + threadIdx.x;
    const int s   = tid >> 3;       // sample
    if (s >= B) return;
    const int k   = tid & 7;        // lane within 8-group

    const float TAU = 0.9f / sqrtf(26.0f);
    const float SIG = TAU;
    const float TS  = TAU * SIG;

    // ---- load sample (8 lanes of a group read the same 6 floats) ----
    float zin0, zin1, zin2, zin3, zin4, zin5;
    {
        const float2* xp = (const float2*)(X + (size_t)s * 6);
        float2 p0 = xp[0], p1 = xp[1], p2 = xp[2];
        zin0 = p0.x; zin1 = p0.y; zin2 = p1.x;
        zin3 = p1.y; zin4 = p2.x; zin5 = p2.y;
    }

    // ---- MLP (redundant across the 8 lanes; dense independent FMA) ----
#define L1ROW(j) float h1_##j = ftanh(b1[j] + DOT6(W1, (j)*6, zin));
    FOR20(L1ROW)
#define L2ROW(j) float h2_##j = ftanh(b2[j] + DOT20(W2, (j)*20, h1_));
    FOR20(L2ROW)
#define L3ROW(j) float h3_##j = ftanh(b3[j] + DOT20(W3, (j)*20, h2_));
    FOR20(L3ROW)
#define ZROW(j)  float z##j  = ftanh(b4[j] + DOT20(W4, (j)*20, h3_));
    FOR8(ZROW)

    // ---- lane selects ----
    const bool lo = (k & 1), mi = (k & 2), hi = (k & 4);
    // zg = z_{pi(k)}, pi = [0,5,3,4,1,6,2,7]
    float a_  = lo ? z5 : z0;
    float b_  = lo ? z4 : z3;
    float c_  = lo ? z6 : z1;
    float d_  = lo ? z7 : z2;
    float e_  = mi ? b_ : a_;
    float f_  = mi ? d_ : c_;
    float zg  = hi ? f_ : e_;
    // sb = SIG * zin_{rho(k)}, rho = [0,1,2,3,5,4,-,-]; lanes 6,7 pinned big
    float a2 = lo ? zin1 : zin0;
    float b2v = lo ? zin3 : zin2;
    float c2 = lo ? zin4 : zin5;
    float e2 = mi ? b2v : a2;
    float sbv = hi ? c2 : e2;
    float sb = (k >= 6) ? 1e30f : SIG * sbv;   // 1e30 pins dummy l1 to 0

    // select masks (precomputed; cndmask in-loop)
    const bool mA  = (k < 2);
    const bool mB  = (k < 4);
    const bool m23 = (k == 2) || (k == 3);
    const bool m45 = (k == 4) || (k == 5);
    const bool mE  = (k == 1) || (k == 2) || (k == 4);
    const bool m5  = (k == 5);

    // ---- PDHG state (per lane: one x-slot, one l1-slot) ----
    float zpt = zg + TAU;
    float xz  = fmaxf(zg, 0.0f) - zg + TAU;   // x - z + TAU
    float q   = 0.0f;                          // TAU * l2
    float p   = xz;                            // xz + q
    float L   = 0.0f;                          // l1_{rho(k)}

#pragma unroll 1
    for (int it = 0; it < NITERS; ++it) {
        // ---- st = (S^T l1)_{pi(k)} ----
        float Lx = qp<1,0,3,2>(L);
        float Qr = L + Lx;            // [Q01,Q01,Q23,Q23,Q45,Q45,0,0]
        float ML = dppmov<HMIR>(L);   // [0,0,l4,l5,l3,l2,l1,l0]
        float A  = qp<0,0,0,2>(L);    // lanes0,1 <- l0
        float Bq = qp<0,0,0,2>(Qr);   // lanes2,3 <- Q01,Q23
        float C  = qp<2,2,1,1>(ML);   // lanes4-7 <- l1,l1,l2,l2
        float t1 = mA ? A : (mB ? Bq : C);
        float D1 = qp<3,3,0,1>(L);    // lanes0,1 <- l3 ; lanes6,7 <- l5,l4
        float D2 = qp<1,1,3,3>(L);    // lanes4,5 <- l4
        float D3 = qp<1,1,3,3>(ML);   // lanes2,3 <- l5
        float t2 = m23 ? D3 : (m45 ? D2 : D1);
        float st = t1 + t2;

        float v = fmaf(-TAU, st, p);

        // ---- ||v||^2 over the 8 lanes (xor1, xor2, half-mirror) ----
        float nl = v * v;
        float n1 = qp<1,0,3,2>(nl);  nl += n1;
        float n2 = qp<2,3,0,1>(nl);  nl += n2;
        float n3 = dppmov<HMIR>(nl); nl += n3;
        float scale = fmaxf(fmaf(-TAU, __builtin_amdgcn_rsqf(nl), 1.0f), 0.0f);

        // ---- component update ----
        float xb = fmaf(scale + scale, v, zpt - xz);  // xbar
        xz = fmaf(scale, v, TAU);
        q  = fmaxf(fmaf(-TS, xb, q), 0.0f);
        p  = xz + q;

        // ---- r = (S xbar)_{rho(k)} = pairsum + single ----
        float Pxp = qp<1,0,3,2>(xb);
        float P   = xb + Pxp;          // [P05,P05,P34,P34,P16,P16,P27,P27]
        float MP  = dppmov<HMIR>(P);   // [P27,P27,P16,P16,P34,P34,P05,P05]
        float E1  = qp<0,0,0,0>(P);    // lanes0-3: P05 ; lanes4-7: P16
        float E2  = qp<0,2,0,0>(MP);   // lane1:P16 lane2:P27 lane4:P34
        float tP  = mE ? E2 : E1;
        float F1  = qp<2,2,3,3>(xb);   // [x3,x3,x4,x4,x2,x2,..]
        float F2  = qp<3,3,3,3>(xb);   // lane5: x7
        float tX  = m5 ? F2 : F1;
        float r   = tP + tX;

        L = fmaxf(fmaf(SIG, r, L) - sb, 0.0f);  // lanes 6,7 clamp to 0
    }

    // x_{pi(k)} = xz + z - TAU
    const int opos = (int)((0x72614350u >> (4 * k)) & 7u);
    out[(size_t)s * 8 + opos] = xz + zg - TAU;
}

extern "C" void kernel_launch(void* const* d_in, const int* in_sizes, int n_in,
                              void* d_out, int out_size, void* d_ws, size_t ws_size,
                              hipStream_t stream) {
    const float* X  = (const float*)d_in[0];
    const float* W1 = (const float*)d_in[1];
    const float* b1 = (const float*)d_in[2];
    const float* W2 = (const float*)d_in[3];
    const float* b2 = (const float*)d_in[4];
    const float* W3 = (const float*)d_in[5];
    const float* b3 = (const float*)d_in[6];
    const float* W4 = (const float*)d_in[7];
    const float* b4 = (const float*)d_in[8];
    float* out = (float*)d_out;
    const int B = in_sizes[0] / 6;
    const int threads = B * 8;
    const int blocks = (threads + 255) / 256;
    hipLaunchKernelGGL(matchnet_kernel, dim3(blocks), dim3(256), 0, stream,
                       X, W1, b1, W2, b2, W3, b3, W4, b4, out, B);
}

// Round 9
// 111.549 us; speedup vs baseline: 1.1803x; 1.1803x over previous
//
#include <hip/hip_runtime.h>
#include <math.h>

// MatchNet: 4-layer tanh MLP (6->20->20->20->8) + 150-iter PDHG QP solve.
// T=4 lanes/sample (2048 waves = 2/SIMD). Cross-round cadence model:
// solo wave ~7.2 cyc/instr, 2 waves ~5.8, 4 waves ~2.0 (saturated). T=4 has
// the lowest per-SIMD instruction total, so this round CUTS instructions:
//  - packed fp32 (v_pk_*) for all slot-A/B elementwise math (<2 x float>)
//  - state substitution w = 2z - x (kills xz and per-iter zpt-xz)
//  - MLP dots pk-packed along K (weight pairs sit in consecutive SGPRs)
// DPP gather sections copied VERBATIM from round-7 (proven); DPP calls stay
// unconditional (round-6 lesson), selects are value-cndmasks.

#define NITERS 150

typedef float v2 __attribute__((ext_vector_type(2)));

__device__ __forceinline__ v2 vfma(v2 a, v2 b, v2 c) {
    return __builtin_elementwise_fma(a, b, c);
}
__device__ __forceinline__ v2 vmax(v2 a, v2 b) {
    return __builtin_elementwise_max(a, b);
}
#define LD2(W, off) (*(const v2*)((W) + (off)))

__device__ __forceinline__ float ftanh(float a) {
    float e = __expf(2.0f * a);
    return fmaf(-2.0f, __builtin_amdgcn_rcpf(e + 1.0f), 1.0f);
}

// quad_perm DPP: lane (q*4+k) reads lane (q*4 + P_k); call unconditionally.
template<int P0, int P1, int P2, int P3>
__device__ __forceinline__ float qp(float x) {
    constexpr int ctrl = P0 | (P1 << 2) | (P2 << 4) | (P3 << 6);
    int xi = __builtin_bit_cast(int, x);
    int yi = __builtin_amdgcn_update_dpp(0, xi, ctrl, 0xF, 0xF, true);
    return __builtin_bit_cast(float, yi);
}

#define FOR20(M) M(0) M(1) M(2) M(3) M(4) M(5) M(6) M(7) M(8) M(9) \
                 M(10) M(11) M(12) M(13) M(14) M(15) M(16) M(17) M(18) M(19)
#define FOR8(M)  M(0) M(1) M(2) M(3) M(4) M(5) M(6) M(7)

// 20-term dot, packed: 2 chains of 5 pk_fma, combined as v2; caller sums .x+.y
#define PK20(W, base, H) \
  ( vfma(LD2(W,(base)+0),H##0, vfma(LD2(W,(base)+4),H##2, vfma(LD2(W,(base)+8),H##4, \
      vfma(LD2(W,(base)+12),H##6, LD2(W,(base)+16)*H##8)))) \
  + vfma(LD2(W,(base)+2),H##1, vfma(LD2(W,(base)+6),H##3, vfma(LD2(W,(base)+10),H##5, \
      vfma(LD2(W,(base)+14),H##7, LD2(W,(base)+18)*H##9)))) )

#define PACK10(P, t) \
  v2 P##0 = {t##_0,  t##_1},  P##1 = {t##_2,  t##_3},  P##2 = {t##_4,  t##_5}; \
  v2 P##3 = {t##_6,  t##_7},  P##4 = {t##_8,  t##_9},  P##5 = {t##_10, t##_11}; \
  v2 P##6 = {t##_12, t##_13}, P##7 = {t##_14, t##_15}, P##8 = {t##_16, t##_17}; \
  v2 P##9 = {t##_18, t##_19};

__global__ __launch_bounds__(256, 2)
void matchnet_kernel(
    const float* __restrict__ X,
    const float* __restrict__ W1, const float* __restrict__ b1,
    const float* __restrict__ W2, const float* __restrict__ b2,
    const float* __restrict__ W3, const float* __restrict__ b3,
    const float* __restrict__ W4, const float* __restrict__ b4,
    float* __restrict__ out, int B)
{
    const int tid = blockIdx.x * 256 + threadIdx.x;
    const int s   = tid >> 2;       // sample
    if (s >= B) return;
    const int g   = tid & 3;        // quad lane

    const float TAU = 0.9f / sqrtf(26.0f);
    const float SIG = TAU;
    const float TS  = TAU * SIG;

    // ---- load sample ----
    float zin0, zin1, zin2, zin3, zin4, zin5;
    v2 zin01, zin23, zin45;
    {
        const float2* xp = (const float2*)(X + (size_t)s * 6);
        float2 p0 = xp[0], p1 = xp[1], p2 = xp[2];
        zin0 = p0.x; zin1 = p0.y; zin2 = p1.x;
        zin3 = p1.y; zin4 = p2.x; zin5 = p2.y;
        zin01 = (v2){p0.x, p0.y}; zin23 = (v2){p1.x, p1.y}; zin45 = (v2){p2.x, p2.y};
    }

    // ---- MLP (redundant across 4 lanes; K-dim pk-packed) ----
#define L1R(j) float t1_##j; { \
        v2 r_ = vfma(LD2(W1,(j)*6+0), zin01, vfma(LD2(W1,(j)*6+2), zin23, LD2(W1,(j)*6+4)*zin45)); \
        t1_##j = ftanh(b1[j] + (r_.x + r_.y)); }
    FOR20(L1R)
    PACK10(A, t1)
#define L2R(j) float t2_##j; { \
        v2 r_ = PK20(W2, (j)*20, A); \
        t2_##j = ftanh(b2[j] + (r_.x + r_.y)); }
    FOR20(L2R)
    PACK10(Bh, t2)
#define L3R(j) float t3_##j; { \
        v2 r_ = PK20(W3, (j)*20, Bh); \
        t3_##j = ftanh(b3[j] + (r_.x + r_.y)); }
    FOR20(L3R)
    PACK10(C, t3)
#define ZR(j) float z##j; { \
        v2 r_ = PK20(W4, (j)*20, C); \
        z##j = ftanh(b4[j] + (r_.x + r_.y)); }
    FOR8(ZR)

    // ---- per-lane selects: zA = z_g, zB = z_{4+g}, sbA/sbB ----
    const bool b0 = (g & 1), b1_ = (g & 2);
    float z01 = b0 ? z1 : z0,  z23 = b0 ? z3 : z2;
    float zA  = b1_ ? z23 : z01;
    float z45 = b0 ? z5 : z4,  z67 = b0 ? z7 : z6;
    float zB  = b1_ ? z67 : z45;

    float i01 = b0 ? zin1 : zin0, i23 = b0 ? zin3 : zin2;
    float igA = b1_ ? i23 : i01;            // zin_g
    float i45 = b0 ? zin5 : zin4;           // zin_{4+g} for g<2
    float sbA = SIG * igA;
    float sbB = (g < 2) ? SIG * i45 : 1e30f;  // 1e30 pins dummy l1B to 0

    // ---- PDHG state (v2 slots: .x = comp g, .y = comp g+4) ----
    // w = 2z - x ; q = TAU*l2 ; p = (x - z + TAU) + q ; lA,lB = l1 duals
    v2 zv = {zA, zB};
    v2 w  = {zA + zA - fmaxf(zA, 0.0f), zB + zB - fmaxf(zB, 0.0f)};
    v2 q  = {0.0f, 0.0f};
    v2 p  = {fmaxf(-zA, 0.0f) + TAU, fmaxf(-zB, 0.0f) + TAU};
    float lA = 0.0f, lB = 0.0f;

    const v2 vTAU  = {TAU, TAU};
    const v2 vmTAU = {-TAU, -TAU};
    const v2 vmTS  = {-TS, -TS};
    const v2 vTWO  = {2.0f, 2.0f};
    const v2 vZERO = {0.0f, 0.0f};

#pragma unroll 1
    for (int it = 0; it < NITERS; ++it) {
        // ---- st = S^T l1 (R7-verbatim DPP gathers) ----
        // stA (cols 0-3): {0,3},{1,4},{2,5},{0,1,5}
        float gA1  = qp<0,1,2,0>(lA);        // [l0,l1,l2,l0]
        float gA2a = qp<3,0,0,1>(lA);
        float gA2b = qp<0,0,1,0>(lB);
        float gA2  = ((g == 0) || (g == 3)) ? gA2a : gA2b;   // [l3,l4,l5,l1]
        float gA3  = qp<2,2,2,1>(lB);        // [0,0,0,l5]
        float stA = (gA1 + gA2) + gA3;
        // stB (cols 4-7): {2,3,5},{0,3},{1,4},{2,4}
        float gB1  = qp<2,0,1,2>(lA);        // [l2,l0,l1,l2]
        float gB2a = qp<3,3,0,0>(lA);
        float gB2b = qp<0,0,0,0>(lB);
        float gB2  = (g < 2) ? gB2a : gB2b;  // [l3,l3,l4,l4]
        float gB3  = qp<1,2,2,2>(lB);        // [l5,0,0,0]
        float stB = (gB1 + gB2) + gB3;

        v2 st = {stA, stB};
        v2 v  = vfma(vmTAU, st, p);          // v = p - TAU*st

        // ---- ||v||^2 over quad ----
        v2 sq = v * v;
        float nl = sq.x + sq.y;
        nl = nl + qp<1,0,3,2>(nl);
        nl = nl + qp<2,3,0,1>(nl);
        float scale = fmaxf(fmaf(-TAU, __builtin_amdgcn_rsqf(nl), 1.0f), 0.0f);
        v2 vscale = {scale, scale};

        // ---- component updates (pk) ----
        v2 sv = vscale * v;                  // x_new - z
        v2 xb = vfma(vTWO, sv, w);           // 2*x_new - x_old
        w = zv - sv;                         // 2z - x_new
        q = vmax(vfma(vmTS, xb, q), vZERO);  // TAU * l2'
        p = (sv + q) + vTAU;                 // (x_new - z + TAU) + q

        float xbA = xb.x, xbB = xb.y;

        // ---- r = S * xbar (R7-verbatim DPP gathers) ----
        // rA (rows 0-3): {0,3,5},{1,3,6},{2,4,7},{0,4,5}
        float h1  = qp<0,1,2,0>(xbA);        // [A0,A1,A2,A0]
        float h2a = qp<3,3,0,0>(xbA);
        float h2b = qp<0,0,0,0>(xbB);
        float h2  = (g < 2) ? h2a : h2b;     // [A3,A3,B0,B0]
        float h3  = qp<1,2,3,1>(xbB);        // [B1,B2,B3,B1]
        float rA = (h1 + h2) + h3;
        // rB (rows 4,5 on lanes 0,1): {1,6,7},{2,3,4}
        float k1  = qp<1,2,0,0>(xbA);        // [A1,A2,.,.]
        float k2a = qp<0,3,0,0>(xbA);
        float k2b = qp<2,0,0,0>(xbB);
        float k2  = (g == 1) ? k2a : k2b;    // [B2,A3,.,.]
        float k3  = qp<3,0,0,0>(xbB);        // [B3,B0,.,.]
        float rB = (k1 + k2) + k3;

        lA = fmaxf(fmaf(SIG, rA, lA) - sbA, 0.0f);
        lB = fmaxf(fmaf(SIG, rB, lB) - sbB, 0.0f);  // lanes 2,3 clamp to 0
    }

    // x = 2z - w
    out[(size_t)s * 8 + g]     = zA + zA - w.x;
    out[(size_t)s * 8 + 4 + g] = zB + zB - w.y;
}

extern "C" void kernel_launch(void* const* d_in, const int* in_sizes, int n_in,
                              void* d_out, int out_size, void* d_ws, size_t ws_size,
                              hipStream_t stream) {
    const float* X  = (const float*)d_in[0];
    const float* W1 = (const float*)d_in[1];
    const float* b1 = (const float*)d_in[2];
    const float* W2 = (const float*)d_in[3];
    const float* b2 = (const float*)d_in[4];
    const float* W3 = (const float*)d_in[5];
    const float* b3 = (const float*)d_in[6];
    const float* W4 = (const float*)d_in[7];
    const float* b4 = (const float*)d_in[8];
    float* out = (float*)d_out;
    const int B = in_sizes[0] / 6;
    const int threads = B * 4;
    const int blocks = (threads + 255) / 256;
    hipLaunchKernelGGL(matchnet_kernel, dim3(blocks), dim3(256), 0, stream,
                       X, W1, b1, W2, b2, W3, b3, W4, b4, out, B);
}

// Round 13
// 109.614 us; speedup vs baseline: 1.2012x; 1.0177x over previous
//
#include <hip/hip_runtime.h>
#include <math.h>

// MatchNet: 4-layer tanh MLP (6->20->20->20->8) + 150-iter PDHG QP solve.
// T=4 lanes/sample, pk-packed fp32, DPP-only cross-lane (R9 structure).
// R10/R12 calibration: |x_100-x_150|=0.123, |x_135-x_150|=0.065 -> the
// reference trajectory is unconverged at 150; truncation is DEAD. N=150.
// This round vs R9: (a) exact off-chain folds (lAms = l1-sb carried;
// svt = sv+TAU computed parallel to xb) — -2 hops on the loop-carried
// chain; (b) update_dpp old=src (not 0): bound_ctrl=1 quad_perm never
// reads OOB so old is dead, but old=0 forced a zero-mov per DPP.

#define NITERS 150

typedef float v2 __attribute__((ext_vector_type(2)));

__device__ __forceinline__ v2 vfma(v2 a, v2 b, v2 c) {
    return __builtin_elementwise_fma(a, b, c);
}
__device__ __forceinline__ v2 vmax(v2 a, v2 b) {
    return __builtin_elementwise_max(a, b);
}
#define LD2(W, off) (*(const v2*)((W) + (off)))

__device__ __forceinline__ float ftanh(float a) {
    float e = __expf(2.0f * a);
    return fmaf(-2.0f, __builtin_amdgcn_rcpf(e + 1.0f), 1.0f);
}

// quad_perm DPP: lane (q*4+k) reads lane (q*4 + P_k); call unconditionally
// (R6 lesson). old=src: with bound_ctrl=1, quad_perm reads are never
// out-of-range, so 'old' is semantically dead; passing src avoids the
// compiler materializing a zero into the dest register first.
template<int P0, int P1, int P2, int P3>
__device__ __forceinline__ float qp(float x) {
    constexpr int ctrl = P0 | (P1 << 2) | (P2 << 4) | (P3 << 6);
    int xi = __builtin_bit_cast(int, x);
    int yi = __builtin_amdgcn_update_dpp(xi, xi, ctrl, 0xF, 0xF, true);
    return __builtin_bit_cast(float, yi);
}

#define FOR20(M) M(0) M(1) M(2) M(3) M(4) M(5) M(6) M(7) M(8) M(9) \
                 M(10) M(11) M(12) M(13) M(14) M(15) M(16) M(17) M(18) M(19)
#define FOR8(M)  M(0) M(1) M(2) M(3) M(4) M(5) M(6) M(7)

// 20-term dot, packed: 2 chains of 5 pk_fma, combined as v2; caller sums .x+.y
#define PK20(W, base, H) \
  ( vfma(LD2(W,(base)+0),H##0, vfma(LD2(W,(base)+4),H##2, vfma(LD2(W,(base)+8),H##4, \
      vfma(LD2(W,(base)+12),H##6, LD2(W,(base)+16)*H##8)))) \
  + vfma(LD2(W,(base)+2),H##1, vfma(LD2(W,(base)+6),H##3, vfma(LD2(W,(base)+10),H##5, \
      vfma(LD2(W,(base)+14),H##7, LD2(W,(base)+18)*H##9)))) )

#define PACK10(P, t) \
  v2 P##0 = {t##_0,  t##_1},  P##1 = {t##_2,  t##_3},  P##2 = {t##_4,  t##_5}; \
  v2 P##3 = {t##_6,  t##_7},  P##4 = {t##_8,  t##_9},  P##5 = {t##_10, t##_11}; \
  v2 P##6 = {t##_12, t##_13}, P##7 = {t##_14, t##_15}, P##8 = {t##_16, t##_17}; \
  v2 P##9 = {t##_18, t##_19};

__global__ __launch_bounds__(256, 2)
void matchnet_kernel(
    const float* __restrict__ X,
    const float* __restrict__ W1, const float* __restrict__ b1,
    const float* __restrict__ W2, const float* __restrict__ b2,
    const float* __restrict__ W3, const float* __restrict__ b3,
    const float* __restrict__ W4, const float* __restrict__ b4,
    float* __restrict__ out, int B)
{
    const int tid = blockIdx.x * 256 + threadIdx.x;
    const int s   = tid >> 2;       // sample
    if (s >= B) return;
    const int g   = tid & 3;        // quad lane

    const float TAU = 0.9f / sqrtf(26.0f);
    const float SIG = TAU;
    const float TS  = TAU * SIG;

    // ---- load sample ----
    float zin0, zin1, zin2, zin3, zin4, zin5;
    v2 zin01, zin23, zin45;
    {
        const float2* xp = (const float2*)(X + (size_t)s * 6);
        float2 p0 = xp[0], p1 = xp[1], p2 = xp[2];
        zin0 = p0.x; zin1 = p0.y; zin2 = p1.x;
        zin3 = p1.y; zin4 = p2.x; zin5 = p2.y;
        zin01 = (v2){p0.x, p0.y}; zin23 = (v2){p1.x, p1.y}; zin45 = (v2){p2.x, p2.y};
    }

    // ---- MLP (redundant across 4 lanes; K-dim pk-packed) ----
#define L1R(j) float t1_##j; { \
        v2 r_ = vfma(LD2(W1,(j)*6+0), zin01, vfma(LD2(W1,(j)*6+2), zin23, LD2(W1,(j)*6+4)*zin45)); \
        t1_##j = ftanh(b1[j] + (r_.x + r_.y)); }
    FOR20(L1R)
    PACK10(A, t1)
#define L2R(j) float t2_##j; { \
        v2 r_ = PK20(W2, (j)*20, A); \
        t2_##j = ftanh(b2[j] + (r_.x + r_.y)); }
    FOR20(L2R)
    PACK10(Bh, t2)
#define L3R(j) float t3_##j; { \
        v2 r_ = PK20(W3, (j)*20, Bh); \
        t3_##j = ftanh(b3[j] + (r_.x + r_.y)); }
    FOR20(L3R)
    PACK10(C, t3)
#define ZR(j) float z##j; { \
        v2 r_ = PK20(W4, (j)*20, C); \
        z##j = ftanh(b4[j] + (r_.x + r_.y)); }
    FOR8(ZR)

    // ---- per-lane selects: zA = z_g, zB = z_{4+g}, sbA/sbB ----
    const bool b0 = (g & 1), b1_ = (g & 2);
    float z01 = b0 ? z1 : z0,  z23 = b0 ? z3 : z2;
    float zA  = b1_ ? z23 : z01;
    float z45 = b0 ? z5 : z4,  z67 = b0 ? z7 : z6;
    float zB  = b1_ ? z67 : z45;

    float i01 = b0 ? zin1 : zin0, i23 = b0 ? zin3 : zin2;
    float igA = b1_ ? i23 : i01;            // zin_g
    float i45 = b0 ? zin5 : zin4;           // zin_{4+g} for g<2
    float sbA = SIG * igA;
    float sbB = (g < 2) ? SIG * i45 : 1e30f;  // 1e30 pins dummy l1B to 0

    // ---- PDHG state (v2 slots: .x = comp g, .y = comp g+4) ----
    // w = 2z - x ; q = TAU*l2 ; p = (x - z + TAU) + q ; lA,lB = l1 duals
    // lAms/lBms = l1 - sb (off-chain carried form)
    v2 zv = {zA, zB};
    v2 w  = {zA + zA - fmaxf(zA, 0.0f), zB + zB - fmaxf(zB, 0.0f)};
    v2 q  = {0.0f, 0.0f};
    v2 p  = {fmaxf(-zA, 0.0f) + TAU, fmaxf(-zB, 0.0f) + TAU};
    float lA = 0.0f, lB = 0.0f;
    float lAms = -sbA, lBms = -sbB;

    const v2 vTAU  = {TAU, TAU};
    const v2 vmTAU = {-TAU, -TAU};
    const v2 vmTS  = {-TS, -TS};
    const v2 vTWO  = {2.0f, 2.0f};
    const v2 vZERO = {0.0f, 0.0f};

#pragma unroll 1
    for (int it = 0; it < NITERS; ++it) {
        // ---- st = S^T l1 (R7-verbatim DPP gathers) ----
        // stA (cols 0-3): {0,3},{1,4},{2,5},{0,1,5}
        float gA1  = qp<0,1,2,0>(lA);        // [l0,l1,l2,l0]
        float gA2a = qp<3,0,0,1>(lA);
        float gA2b = qp<0,0,1,0>(lB);
        float gA2  = ((g == 0) || (g == 3)) ? gA2a : gA2b;   // [l3,l4,l5,l1]
        float gA3  = qp<2,2,2,1>(lB);        // [0,0,0,l5]
        float stA = (gA1 + gA2) + gA3;
        // stB (cols 4-7): {2,3,5},{0,3},{1,4},{2,4}
        float gB1  = qp<2,0,1,2>(lA);        // [l2,l0,l1,l2]
        float gB2a = qp<3,3,0,0>(lA);
        float gB2b = qp<0,0,0,0>(lB);
        float gB2  = (g < 2) ? gB2a : gB2b;  // [l3,l3,l4,l4]
        float gB3  = qp<1,2,2,2>(lB);        // [l5,0,0,0]
        float stB = (gB1 + gB2) + gB3;

        v2 st = {stA, stB};
        v2 v  = vfma(vmTAU, st, p);          // v = p - TAU*st

        // ---- ||v||^2 over quad ----
        v2 sq = v * v;
        float nl = sq.x + sq.y;
        nl = nl + qp<1,0,3,2>(nl);
        nl = nl + qp<2,3,0,1>(nl);
        float scale = fmaxf(fmaf(-TAU, __builtin_amdgcn_rsqf(nl), 1.0f), 0.0f);
        v2 vscale = {scale, scale};

        // ---- component updates (pk) ----
        v2 sv  = vscale * v;                 // x_new - z
        v2 xb  = vfma(vTWO, sv, w);          // 2*x_new - x_old
        v2 svt = sv + vTAU;                  // off xb-chain: sv + TAU
        w = zv - sv;                         // 2z - x_new
        q = vmax(vfma(vmTS, xb, q), vZERO);  // TAU * l2'
        p = svt + q;                         // (x_new - z + TAU) + q

        float xbA = xb.x, xbB = xb.y;

        // ---- r = S * xbar (R7-verbatim DPP gathers) ----
        // rA (rows 0-3): {0,3,5},{1,3,6},{2,4,7},{0,4,5}
        float h1  = qp<0,1,2,0>(xbA);        // [A0,A1,A2,A0]
        float h2a = qp<3,3,0,0>(xbA);
        float h2b = qp<0,0,0,0>(xbB);
        float h2  = (g < 2) ? h2a : h2b;     // [A3,A3,B0,B0]
        float h3  = qp<1,2,3,1>(xbB);        // [B1,B2,B3,B1]
        float rA = (h1 + h2) + h3;
        // rB (rows 4,5 on lanes 0,1): {1,6,7},{2,3,4}
        float k1  = qp<1,2,0,0>(xbA);        // [A1,A2,.,.]
        float k2a = qp<0,3,0,0>(xbA);
        float k2b = qp<2,0,0,0>(xbB);
        float k2  = (g == 1) ? k2a : k2b;    // [B2,A3,.,.]
        float k3  = qp<3,0,0,0>(xbB);        // [B3,B0,.,.]
        float rB = (k1 + k2) + k3;

        // l1 update: fma into (l1 - sb), clamp; recompute carried forms
        lA = fmaxf(fmaf(SIG, rA, lAms), 0.0f);
        lB = fmaxf(fmaf(SIG, rB, lBms), 0.0f);  // lanes 2,3 clamp to 0
        lAms = lA - sbA;                     // off critical path
        lBms = lB - sbB;
    }

    // x = 2z - w
    out[(size_t)s * 8 + g]     = zA + zA - w.x;
    out[(size_t)s * 8 + 4 + g] = zB + zB - w.y;
}

extern "C" void kernel_launch(void* const* d_in, const int* in_sizes, int n_in,
                              void* d_out, int out_size, void* d_ws, size_t ws_size,
                              hipStream_t stream) {
    const float* X  = (const float*)d_in[0];
    const float* W1 = (const float*)d_in[1];
    const float* b1 = (const float*)d_in[2];
    const float* W2 = (const float*)d_in[3];
    const float* b2 = (const float*)d_in[4];
    const float* W3 = (const float*)d_in[5];
    const float* b3 = (const float*)d_in[6];
    const float* W4 = (const float*)d_in[7];
    const float* b4 = (const float*)d_in[8];
    float* out = (float*)d_out;
    const int B = in_sizes[0] / 6;
    const int threads = B * 4;
    const int blocks = (threads + 255) / 256;
    hipLaunchKernelGGL(matchnet_kernel, dim3(blocks), dim3(256), 0, stream,
                       X, W1, b1, W2, b2, W3, b3, W4, b4, out, B);
}